// Round 8
// baseline (497.186 us; speedup 1.0000x reference)
//
#include <hip/hip_runtime.h>
#include <math.h>

// Problem constants
#define NPTS   131072          // 32*64*64 points
#define DIMS   64              // embedding dim / channels
#define KCODES 512             // codebook size
#define HW     4096            // 64*64 spatial

// d_out flat offsets (floats), reference tuple order:
// (loss, quantized_out[NCHW], perplexity, encodings, quantized_flat)
#define OFF_LOSS 0
#define OFF_QOUT 1
#define OFF_PERP 8388609
#define OFF_ENC  8388610
#define OFF_QF   75497474   // 8388610 + 67108864

// d_ws byte offsets
#define WS_HIST  0          // unsigned[512]  (memset to 0 each call)
#define WS_BLOSS 2048       // float[1024]
#define WS_NRM   10240      // float[512]
#define WS_EH    12288      // ushort[512*64] bf16 hi, MFMA-fragment order
#define WS_EL    77824      // ushort[512*64] bf16 lo, MFMA-fragment order

#define EPS_MARGIN 0.02f    // split-bf16 distance error <~2.4e-4; 80x cushion

typedef __attribute__((ext_vector_type(8))) short short8;
typedef __attribute__((ext_vector_type(4))) float f32x4;

// Cross-kernel handoff: chosen code index per point.
__device__ int g_fidx[NPTS];

__device__ __forceinline__ unsigned short f2bf(float f) {
    unsigned u = __float_as_uint(f);
    unsigned r = (u + 0x7fffu + ((u >> 16) & 1u)) >> 16;   // RNE
    return (unsigned short)r;
}
__device__ __forceinline__ float bf2f(unsigned short h) {
    return __uint_as_float(((unsigned)h) << 16);
}

// ---------------------------------------------------------------------------
// Prep: split codebook into bf16 hi/lo in MFMA B-fragment order:
//   idx = ((t*2 + s)*64 + quad*16 + col)*8 + j,  k = t*16+col, d = s*32+quad*8+j
// so vq_main's lane l loads short8 at [(t*2+s)*64 + l] -> fully coalesced.
// ---------------------------------------------------------------------------
__global__ void vq_prep(const float* __restrict__ emb,
                        unsigned short* __restrict__ ehF,
                        unsigned short* __restrict__ elF,
                        float* __restrict__ nrm)
{
    int k = blockIdx.x;      // 512
    int d = threadIdx.x;     // 64
    float v = emb[k * DIMS + d];
    unsigned short h = f2bf(v);
    int t = k >> 4, col = k & 15;
    int s = d >> 5, quad = (d >> 3) & 3, j = d & 7;
    int idx = (((t * 2 + s) * 64) + quad * 16 + col) * 8 + j;
    ehF[idx] = h;
    elF[idx] = f2bf(v - bf2f(h));
    double sq = (double)v * (double)v;
    #pragma unroll
    for (int off = 32; off > 0; off >>= 1)
        sq += __shfl_down(sq, off, 64);
    if (d == 0) nrm[k] = (float)sq;
}

// ---------------------------------------------------------------------------
// Main: 128 points/block, 32 points/wave (2 A-sets -> each B-fragment load
// feeds 12 MFMAs, halving L2 B-traffic vs round 7). Split-bf16 MFMA
// distances; argmin w/ second-best margin; fp64 re-scan of near-ties.
// NOTE: (256,2) is load-bearing — higher min-occupancy caps VGPR at 64 and
// spills ~370 MB of scratch (measured rounds 2 & 5).
// ---------------------------------------------------------------------------
__global__ __launch_bounds__(256, 2) void vq_main(
    const float*          __restrict__ in,    // NCHW [32][64][64][64]
    const float*          __restrict__ emb,   // [512][64] fp32 (recheck)
    const unsigned short* __restrict__ eh,    // frag-order bf16 hi
    const unsigned short* __restrict__ el,    // frag-order bf16 lo
    const float*          __restrict__ nrm,   // [512] ||e||^2 fp32
    unsigned*             __restrict__ hist,  // [512]
    float*                __restrict__ bloss) // [1024]
{
    __shared__ float xs[128 * 68];     // [p][d] x-tile, stride 68 (34.8 KB)
    __shared__ float ns[512];
    __shared__ float psx[256];
    __shared__ float pdist[128];
    __shared__ int   fidx[128];
    __shared__ int   flagged[128];
    __shared__ int   nflag;
    __shared__ double rv[4];
    __shared__ int    ri[4];
    // ~41 KB -> 2 blocks/CU

    const int tid  = threadIdx.x;

    const int blk = blockIdx.x;          // 1024
    const int b   = blk >> 5;            // batch 0..31
    const int hw0 = (blk & 31) * 128;    // spatial tile start
    const long inBase = (long)b * (DIMS * HW) + hw0;

    // ---- stage x tile [p][d]: 128 pts x 64 dims, coalesced ----
    {
        int sp   = tid & 127;            // point
        int half = tid >> 7;             // dim half 0/1
        float ps = 0.f;
        #pragma unroll
        for (int i = 0; i < 32; i++) {
            int d = half * 32 + i;
            float v = in[inBase + (long)d * HW + sp];
            xs[sp * 68 + d] = v;
            ps = fmaf(v, v, ps);
        }
        psx[tid] = ps;                   // psx[half*128 + sp]
    }
    ns[tid] = nrm[tid];
    ns[tid + 256] = nrm[tid + 256];
    if (tid == 0) nflag = 0;
    __syncthreads();

    // ---- wave-level MFMA scan: 32 points x 512 codes per wave ----
    const int wid   = tid >> 6;          // wave 0..3
    const int l     = tid & 63;
    const int col   = l & 15;
    const int quad  = l >> 4;
    const int pbase = wid * 32;

    short8 ah[2][2], al[2][2];           // [set][k-slice]
    #pragma unroll
    for (int u = 0; u < 2; u++) {
        const float* xrow = &xs[(pbase + u * 16 + col) * 68];
        #pragma unroll
        for (int s = 0; s < 2; s++) {
            int k0 = s * 32 + quad * 8;
            float xv[8];
            *(float4*)&xv[0] = *(const float4*)&xrow[k0];
            *(float4*)&xv[4] = *(const float4*)&xrow[k0 + 4];
            short8 h, lo;
            #pragma unroll
            for (int j = 0; j < 8; j++) {
                unsigned short hb = f2bf(xv[j]);
                h[j]  = (short)hb;
                lo[j] = (short)f2bf(xv[j] - bf2f(hb));
            }
            ah[u][s] = h; al[u][s] = lo;
        }
    }

    float b1[2][4], b2[2][4];
    int   i1[2][4];
    #pragma unroll
    for (int u = 0; u < 2; u++)
        #pragma unroll
        for (int r = 0; r < 4; r++) { b1[u][r] = 1e30f; b2[u][r] = 1e30f; i1[u][r] = 0; }

    {
        const short8* bhF = (const short8*)eh;   // [(t*2+s)*64 + lane]
        const short8* blF = (const short8*)el;
        for (int t = 0; t < 32; t++) {
            short8 bh0 = bhF[(t * 2    ) * 64 + l];   // coalesced 1 KB/instr
            short8 bh1 = bhF[(t * 2 + 1) * 64 + l];
            short8 bl0 = blF[(t * 2    ) * 64 + l];
            short8 bl1 = blF[(t * 2 + 1) * 64 + l];

            f32x4 acc[2] = {{0.f,0.f,0.f,0.f},{0.f,0.f,0.f,0.f}};
            #pragma unroll
            for (int u = 0; u < 2; u++) {
                acc[u] = __builtin_amdgcn_mfma_f32_16x16x32_bf16(ah[u][0], bh0, acc[u], 0, 0, 0);
                acc[u] = __builtin_amdgcn_mfma_f32_16x16x32_bf16(ah[u][1], bh1, acc[u], 0, 0, 0);
                acc[u] = __builtin_amdgcn_mfma_f32_16x16x32_bf16(ah[u][0], bl0, acc[u], 0, 0, 0);
                acc[u] = __builtin_amdgcn_mfma_f32_16x16x32_bf16(ah[u][1], bl1, acc[u], 0, 0, 0);
                acc[u] = __builtin_amdgcn_mfma_f32_16x16x32_bf16(al[u][0], bh0, acc[u], 0, 0, 0);
                acc[u] = __builtin_amdgcn_mfma_f32_16x16x32_bf16(al[u][1], bh1, acc[u], 0, 0, 0);
            }

            int   k  = t * 16 + col;
            float nk = ns[k];
            #pragma unroll
            for (int u = 0; u < 2; u++)
                #pragma unroll
                for (int r = 0; r < 4; r++) {
                    float v = fmaf(-2.f, acc[u][r], nk);   // ||e||^2 - 2 x.e
                    bool better = (v < b1[u][r]);
                    b2[u][r] = better ? b1[u][r] : fminf(b2[u][r], v);
                    i1[u][r] = better ? k : i1[u][r];
                    b1[u][r] = better ? v : b1[u][r];
                }
        }
    }

    // ---- reduce over 16 code-columns ----
    #pragma unroll
    for (int u = 0; u < 2; u++)
        #pragma unroll
        for (int r = 0; r < 4; r++) {
            float b1v = b1[u][r], b2v = b2[u][r];
            int   i1v = i1[u][r];
            #pragma unroll
            for (int m = 1; m < 16; m <<= 1) {
                float ob1 = __shfl_xor(b1v, m);
                int   oi1 = __shfl_xor(i1v, m);
                float ob2 = __shfl_xor(b2v, m);
                float loser = fmaxf(b1v, ob1);
                b2v = fminf(fminf(b2v, ob2), loser);
                if (ob1 < b1v || (ob1 == b1v && oi1 < i1v)) { b1v = ob1; i1v = oi1; }
            }
            if (col == 0) {
                int p = pbase + u * 16 + quad * 4 + r;   // D row = quad*4 + reg
                fidx[p] = i1v;
                float sx = psx[p] + psx[128 + p];
                pdist[p] = sx + b1v;
                if (b2v - b1v < EPS_MARGIN) {
                    int s = atomicAdd(&nflag, 1);
                    flagged[s] = p;
                }
            }
        }
    __syncthreads();

    // ---- fp64 cooperative re-scan for near-tie points ----
    {
        int nf = nflag;
        for (int f = 0; f < nf; f++) {
            int p = flagged[f];
            double bd = 1e300;
            int    bk = 1 << 30;
            #pragma unroll
            for (int kk = 0; kk < 2; kk++) {
                int k = tid * 2 + kk;
                const float4* er = (const float4*)(emb + k * DIMS);
                double s = 0.0;
                #pragma unroll 4
                for (int i = 0; i < 16; i++) {
                    float4 e4 = er[i];
                    double d0 = (double)xs[p * 68 + i * 4    ] - (double)e4.x;
                    double d1 = (double)xs[p * 68 + i * 4 + 1] - (double)e4.y;
                    double d2 = (double)xs[p * 68 + i * 4 + 2] - (double)e4.z;
                    double d3 = (double)xs[p * 68 + i * 4 + 3] - (double)e4.w;
                    s = fma(d0, d0, s); s = fma(d1, d1, s);
                    s = fma(d2, d2, s); s = fma(d3, d3, s);
                }
                if (s < bd || (s == bd && k < bk)) { bd = s; bk = k; }
            }
            #pragma unroll
            for (int off = 32; off > 0; off >>= 1) {
                double ov = __shfl_down(bd, off);
                int    ok = __shfl_down(bk, off);
                if (ov < bd || (ov == bd && ok < bk)) { bd = ov; bk = ok; }
            }
            if ((tid & 63) == 0) { rv[tid >> 6] = bd; ri[tid >> 6] = bk; }
            __syncthreads();
            if (tid == 0) {
                double fbd = rv[0]; int fbk = ri[0];
                for (int w = 1; w < 4; w++) {
                    if (rv[w] < fbd || (rv[w] == fbd && ri[w] < fbk)) { fbd = rv[w]; fbk = ri[w]; }
                }
                fidx[p] = fbk;
                pdist[p] = (float)fbd;
            }
            __syncthreads();
        }
    }

    // ---- emit: fidx to global, histogram, loss partial ----
    if (tid < 128) {
        int bi = fidx[tid];
        g_fidx[b * HW + hw0 + tid] = bi;
        atomicAdd(&hist[bi], 1u);
    }
    if (tid < 64) {
        float lp = pdist[tid] + pdist[tid + 64];
        #pragma unroll
        for (int off = 32; off > 0; off >>= 1)
            lp += __shfl_down(lp, off);
        if (tid == 0) bloss[blk] = lp;
    }
}

// ---------------------------------------------------------------------------
// Streaming output writer: high occupancy, nontemporal stores.
// Writes encodings (268 MB), quantized_flat (33.5 MB), quantized_out (33.5 MB).
// ---------------------------------------------------------------------------
__global__ __launch_bounds__(256, 8) void vq_out(
    const float* __restrict__ emb,
    float*       __restrict__ out)
{
    __shared__ float qs[64 * 65];   // chosen rows [p][d], stride 65 (16.25 KB)
    __shared__ int   fidx[64];

    const int tid  = threadIdx.x;

    const int blk = blockIdx.x;          // 2048
    const int b   = blk >> 6;
    const int hw0 = (blk & 63) * 64;
    const int n0  = b * HW + hw0;

    if (tid < 64) fidx[tid] = g_fidx[n0 + tid];
    __syncthreads();

    // gather chosen embedding rows into LDS
    {
        int q = tid & 3, p = tid >> 2;
        int row = fidx[p];
        const float4* src = (const float4*)(emb + row * DIMS + q * 16);
        #pragma unroll
        for (int i = 0; i < 4; i++) {
            float4 v = src[i];
            int base = p * 65 + q * 16 + i * 4;
            qs[base] = v.x; qs[base + 1] = v.y; qs[base + 2] = v.z; qs[base + 3] = v.w;
        }
    }
    __syncthreads();

    // ---- encodings: full one-hot rows, nontemporal 16B stores ----
    {
        float* encB = out + (long)OFF_ENC + (long)n0 * KCODES;
        #pragma unroll 4
        for (int i = 0; i < 32; i++) {
            int f  = i * 1024 + tid * 4;
            int p  = f >> 9;
            int k0 = f & 511;
            int fd = fidx[p];
            f32x4 v;
            v.x = (k0     == fd) ? 1.0f : 0.0f;
            v.y = (k0 + 1 == fd) ? 1.0f : 0.0f;
            v.z = (k0 + 2 == fd) ? 1.0f : 0.0f;
            v.w = (k0 + 3 == fd) ? 1.0f : 0.0f;
            __builtin_nontemporal_store(v, (f32x4*)(encB + f));
        }
    }

    // ---- quantized_flat [n][64] ----
    {
        float* qfB = out + (long)OFF_QF + (long)n0 * DIMS;
        #pragma unroll
        for (int i = 0; i < 4; i++) {
            int f = i * 1024 + tid * 4;
            int p = f >> 6;
            int d = f & 63;
            f32x4 v;
            v.x = qs[p * 65 + d];     v.y = qs[p * 65 + d + 1];
            v.z = qs[p * 65 + d + 2]; v.w = qs[p * 65 + d + 3];
            __builtin_nontemporal_store(v, (f32x4*)(qfB + f));
        }
    }

    // ---- quantized_out NCHW: 1024 float4 per block (4/thread) ----
    {
        float* qoB = out + (long)OFF_QOUT + (long)b * (DIMS * HW) + hw0;
        #pragma unroll
        for (int i = 0; i < 4; i++) {
            int f4  = i * 256 + tid;
            int d   = f4 >> 4;        // row 0..63
            int seg = f4 & 15;        // float4 segment within row
            f32x4 v;
            v.x = qs[(seg * 4    ) * 65 + d];
            v.y = qs[(seg * 4 + 1) * 65 + d];
            v.z = qs[(seg * 4 + 2) * 65 + d];
            v.w = qs[(seg * 4 + 3) * 65 + d];
            __builtin_nontemporal_store(v, (f32x4*)(qoB + (long)d * HW + seg * 4));
        }
    }
}

// ---------------------------------------------------------------------------
// Finalize: loss scalar + perplexity (fp64)
// ---------------------------------------------------------------------------
__global__ void vq_finalize(const unsigned* __restrict__ hist,
                            const float* __restrict__ bloss,
                            float* __restrict__ out)
{
    __shared__ double sl[512];
    __shared__ double sh[512];
    int tid = threadIdx.x;   // 512

    double l = (double)bloss[tid] + (double)bloss[tid + 512];

    unsigned c = hist[tid];
    double p = (double)c * (1.0 / 131072.0);
    double h = p * log(p + 1e-10);

    sl[tid] = l;
    sh[tid] = h;
    __syncthreads();
    for (int s = 256; s > 0; s >>= 1) {
        if (tid < s) { sl[tid] += sl[tid + s]; sh[tid] += sh[tid + s]; }
        __syncthreads();
    }
    if (tid == 0) {
        out[OFF_LOSS] = (float)(0.25 * sl[0] / 8388608.0);
        out[OFF_PERP] = (float)exp(-sh[0]);
    }
}

// ---------------------------------------------------------------------------
extern "C" void kernel_launch(void* const* d_in, const int* in_sizes, int n_in,
                              void* d_out, int out_size, void* d_ws, size_t ws_size,
                              hipStream_t stream)
{
    const float* in  = (const float*)d_in[0];   // inputs  [32,64,64,64] f32
    const float* emb = (const float*)d_in[1];   // codebook [512,64] f32
    float* out = (float*)d_out;
    char*  ws  = (char*)d_ws;

    unsigned*       hist  = (unsigned*)      (ws + WS_HIST);
    float*          bloss = (float*)         (ws + WS_BLOSS);
    float*          nrm   = (float*)         (ws + WS_NRM);
    unsigned short* eh    = (unsigned short*)(ws + WS_EH);
    unsigned short* el    = (unsigned short*)(ws + WS_EL);

    (void)hipMemsetAsync(hist, 0, 2048, stream);
    vq_prep<<<KCODES, 64, 0, stream>>>(emb, eh, el, nrm);
    vq_main<<<1024, 256, 0, stream>>>(in, emb, eh, el, nrm, hist, bloss);
    vq_out<<<2048, 256, 0, stream>>>(emb, out);
    vq_finalize<<<1, 512, 0, stream>>>(hist, bloss, out);
}

// Round 9
// 418.613 us; speedup vs baseline: 1.1877x; 1.1877x over previous
//
#include <hip/hip_runtime.h>
#include <math.h>

// Problem constants
#define NPTS   131072          // 32*64*64 points
#define DIMS   64              // embedding dim / channels
#define KCODES 512             // codebook size
#define HW     4096            // 64*64 spatial

// d_out flat offsets (floats), reference tuple order:
// (loss, quantized_out[NCHW], perplexity, encodings, quantized_flat)
#define OFF_LOSS 0
#define OFF_QOUT 1
#define OFF_PERP 8388609
#define OFF_ENC  8388610
#define OFF_QF   75497474   // 8388610 + 67108864

// d_ws byte offsets
#define WS_HIST  0          // unsigned[512]  (zeroed by vq_prep)
#define WS_BLOSS 2048       // float[2048]
#define WS_NRM   10240      // float[512]
#define WS_EH    12288      // ushort[512*64] bf16 hi, MFMA-fragment order
#define WS_EL    77824      // ushort[512*64] bf16 lo, MFMA-fragment order

#define EPS_MARGIN 0.02f    // split-bf16 distance error <~2.4e-4; 80x cushion

typedef __attribute__((ext_vector_type(8))) short short8;
typedef __attribute__((ext_vector_type(4))) float f32x4;

__device__ __forceinline__ unsigned short f2bf(float f) {
    unsigned u = __float_as_uint(f);
    unsigned r = (u + 0x7fffu + ((u >> 16) & 1u)) >> 16;   // RNE
    return (unsigned short)r;
}
__device__ __forceinline__ float bf2f(unsigned short h) {
    return __uint_as_float(((unsigned)h) << 16);
}

// ---------------------------------------------------------------------------
// Prep: split codebook into bf16 hi/lo in MFMA B-fragment order:
//   idx = ((t*2 + s)*64 + quad*16 + col)*8 + j,  k = t*16+col, d = s*32+quad*8+j
// so vq_fused's lane l loads short8 at [(t*2+s)*64 + l] -> fully coalesced.
// Also zeroes hist (replaces a separate memset dispatch).
// ---------------------------------------------------------------------------
__global__ void vq_prep(const float* __restrict__ emb,
                        unsigned short* __restrict__ ehF,
                        unsigned short* __restrict__ elF,
                        float* __restrict__ nrm,
                        unsigned* __restrict__ hist)
{
    int k = blockIdx.x;      // 512
    int d = threadIdx.x;     // 64
    float v = emb[k * DIMS + d];
    unsigned short h = f2bf(v);
    int t = k >> 4, col = k & 15;
    int s = d >> 5, quad = (d >> 3) & 3, j = d & 7;
    int idx = (((t * 2 + s) * 64) + quad * 16 + col) * 8 + j;
    ehF[idx] = h;
    elF[idx] = f2bf(v - bf2f(h));
    double sq = (double)v * (double)v;
    #pragma unroll
    for (int off = 32; off > 0; off >>= 1)
        sq += __shfl_down(sq, off, 64);
    if (d == 0) { nrm[k] = (float)sq; hist[k] = 0u; }
}

// ---------------------------------------------------------------------------
// Fused: 64 points/block. Split-bf16 MFMA distances (coalesced frag-order B),
// argmin w/ second-best margin, fp64 re-scan of near-ties, then ALL output
// writes inline (nontemporal). Store drain of one block overlaps compute of
// sibling blocks on the same CU (fillBuffer evidence: few waves of pure
// streaming stores saturate HBM).
// NOTE: (256,2) is load-bearing — higher min-occupancy caps VGPR at 64 and
// spills ~370 MB of scratch (measured rounds 2 & 5).
// ---------------------------------------------------------------------------
__global__ __launch_bounds__(256, 2) void vq_fused(
    const float*          __restrict__ in,    // NCHW [32][64][64][64]
    const float*          __restrict__ emb,   // [512][64] fp32 (recheck+gather)
    const unsigned short* __restrict__ eh,    // frag-order bf16 hi
    const unsigned short* __restrict__ el,    // frag-order bf16 lo
    const float*          __restrict__ nrm,   // [512] ||e||^2 fp32
    unsigned*             __restrict__ hist,  // [512]
    float*                __restrict__ bloss, // [2048]
    float*                __restrict__ out)
{
    __shared__ float xs[64 * 68];      // [p][d] x-tile, stride 68 (17 KB); reused as qs
    __shared__ float ns[512];
    __shared__ float psx[256];
    __shared__ float pdist[64];
    __shared__ int   fidx[64];
    __shared__ int   flagged[64];
    __shared__ int   nflag;
    __shared__ double rv[4];
    __shared__ int    ri[4];
    // ~22 KB

    const int tid  = threadIdx.x;
    const int lane = tid & 63;
    const int dg   = tid >> 6;

    const int blk = blockIdx.x;          // 2048
    const int b   = blk >> 6;
    const int hw0 = (blk & 63) * 64;
    const long inBase = (long)b * (DIMS * HW) + hw0;

    // ---- stage x tile [p][d] ----
    {
        float ps = 0.f;
        #pragma unroll
        for (int i = 0; i < 16; i++) {
            int d = dg * 16 + i;
            float v = in[inBase + (long)d * HW + lane];
            xs[lane * 68 + d] = v;
            ps = fmaf(v, v, ps);
        }
        psx[tid] = ps;
    }
    ns[tid] = nrm[tid];
    ns[tid + 256] = nrm[tid + 256];
    if (tid == 0) nflag = 0;
    __syncthreads();

    // ---- wave-level MFMA distance scan: 16 points x 512 codes per wave ----
    const int wid   = tid >> 6;
    const int l     = tid & 63;
    const int col   = l & 15;
    const int quad  = l >> 4;
    const int pbase = wid * 16;

    short8 ah[2], al[2];
    {
        const float* xrow = &xs[(pbase + col) * 68];
        #pragma unroll
        for (int s = 0; s < 2; s++) {
            int k0 = s * 32 + quad * 8;
            float xv[8];
            *(float4*)&xv[0] = *(const float4*)&xrow[k0];
            *(float4*)&xv[4] = *(const float4*)&xrow[k0 + 4];
            short8 h, lo;
            #pragma unroll
            for (int j = 0; j < 8; j++) {
                unsigned short hb = f2bf(xv[j]);
                h[j]  = (short)hb;
                lo[j] = (short)f2bf(xv[j] - bf2f(hb));
            }
            ah[s] = h; al[s] = lo;
        }
    }

    float b1[4], b2[4];
    int   i1[4];
    #pragma unroll
    for (int r = 0; r < 4; r++) { b1[r] = 1e30f; b2[r] = 1e30f; i1[r] = 0; }

    {
        const short8* bhF = (const short8*)eh;   // [(t*2+s)*64 + lane]
        const short8* blF = (const short8*)el;
        for (int t = 0; t < 32; t++) {
            short8 bh0 = bhF[(t * 2    ) * 64 + l];   // coalesced 1 KB/instr
            short8 bh1 = bhF[(t * 2 + 1) * 64 + l];
            short8 bl0 = blF[(t * 2    ) * 64 + l];
            short8 bl1 = blF[(t * 2 + 1) * 64 + l];

            f32x4 acc = {0.f, 0.f, 0.f, 0.f};
            acc = __builtin_amdgcn_mfma_f32_16x16x32_bf16(ah[0], bh0, acc, 0, 0, 0);
            acc = __builtin_amdgcn_mfma_f32_16x16x32_bf16(ah[1], bh1, acc, 0, 0, 0);
            acc = __builtin_amdgcn_mfma_f32_16x16x32_bf16(ah[0], bl0, acc, 0, 0, 0);
            acc = __builtin_amdgcn_mfma_f32_16x16x32_bf16(ah[1], bl1, acc, 0, 0, 0);
            acc = __builtin_amdgcn_mfma_f32_16x16x32_bf16(al[0], bh0, acc, 0, 0, 0);
            acc = __builtin_amdgcn_mfma_f32_16x16x32_bf16(al[1], bh1, acc, 0, 0, 0);

            int   k  = t * 16 + col;
            float nk = ns[k];
            #pragma unroll
            for (int r = 0; r < 4; r++) {
                float v = fmaf(-2.f, acc[r], nk);   // ||e||^2 - 2 x.e
                bool better = (v < b1[r]);
                b2[r] = better ? b1[r] : fminf(b2[r], v);
                i1[r] = better ? k : i1[r];
                b1[r] = better ? v : b1[r];
            }
        }
    }

    // ---- reduce over 16 code-columns ----
    #pragma unroll
    for (int r = 0; r < 4; r++) {
        float b1v = b1[r], b2v = b2[r];
        int   i1v = i1[r];
        #pragma unroll
        for (int m = 1; m < 16; m <<= 1) {
            float ob1 = __shfl_xor(b1v, m);
            int   oi1 = __shfl_xor(i1v, m);
            float ob2 = __shfl_xor(b2v, m);
            float loser = fmaxf(b1v, ob1);
            b2v = fminf(fminf(b2v, ob2), loser);
            if (ob1 < b1v || (ob1 == b1v && oi1 < i1v)) { b1v = ob1; i1v = oi1; }
        }
        if (col == 0) {
            int p = pbase + quad * 4 + r;    // D row = quad*4 + reg
            fidx[p] = i1v;
            float sx = psx[p] + psx[64 + p] + psx[128 + p] + psx[192 + p];
            pdist[p] = sx + b1v;
            if (b2v - b1v < EPS_MARGIN) {
                int s = atomicAdd(&nflag, 1);
                flagged[s] = p;
            }
        }
    }
    __syncthreads();

    // ---- fp64 cooperative re-scan for near-tie points ----
    {
        int nf = nflag;
        for (int f = 0; f < nf; f++) {
            int p = flagged[f];
            double bd = 1e300;
            int    bk = 1 << 30;
            #pragma unroll
            for (int kk = 0; kk < 2; kk++) {
                int k = tid * 2 + kk;
                const float4* er = (const float4*)(emb + k * DIMS);
                double s = 0.0;
                #pragma unroll 4
                for (int i = 0; i < 16; i++) {
                    float4 e4 = er[i];
                    double d0 = (double)xs[p * 68 + i * 4    ] - (double)e4.x;
                    double d1 = (double)xs[p * 68 + i * 4 + 1] - (double)e4.y;
                    double d2 = (double)xs[p * 68 + i * 4 + 2] - (double)e4.z;
                    double d3 = (double)xs[p * 68 + i * 4 + 3] - (double)e4.w;
                    s = fma(d0, d0, s); s = fma(d1, d1, s);
                    s = fma(d2, d2, s); s = fma(d3, d3, s);
                }
                if (s < bd || (s == bd && k < bk)) { bd = s; bk = k; }
            }
            #pragma unroll
            for (int off = 32; off > 0; off >>= 1) {
                double ov = __shfl_down(bd, off);
                int    ok = __shfl_down(bk, off);
                if (ov < bd || (ov == bd && ok < bk)) { bd = ov; bk = ok; }
            }
            if ((tid & 63) == 0) { rv[tid >> 6] = bd; ri[tid >> 6] = bk; }
            __syncthreads();
            if (tid == 0) {
                double fbd = rv[0]; int fbk = ri[0];
                for (int w = 1; w < 4; w++) {
                    if (rv[w] < fbd || (rv[w] == fbd && ri[w] < fbk)) { fbd = rv[w]; fbk = ri[w]; }
                }
                fidx[p] = fbk;
                pdist[p] = (float)fbd;
            }
            __syncthreads();
        }
    }

    // ---- histogram + loss partial ----
    if (tid < 64) {
        atomicAdd(&hist[fidx[tid]], 1u);
        float lp = pdist[tid];
        #pragma unroll
        for (int off = 32; off > 0; off >>= 1)
            lp += __shfl_down(lp, off);
        if (tid == 0) bloss[blk] = lp;
    }
    __syncthreads();   // all xs reads done before qs overwrite

    // ---- stage chosen embedding rows into qs (aliases xs, stride 65) ----
    float* qs = xs;
    {
        int q = tid & 3, p = tid >> 2;
        int row = fidx[p];
        const float4* src = (const float4*)(emb + row * DIMS + q * 16);
        #pragma unroll
        for (int i = 0; i < 4; i++) {
            float4 v = src[i];
            int base = p * 65 + q * 16 + i * 4;
            qs[base] = v.x; qs[base + 1] = v.y; qs[base + 2] = v.z; qs[base + 3] = v.w;
        }
    }

    const int n0 = b * HW + hw0;

    // ---- encodings: full one-hot rows (needs only fidx; overlaps staging) ----
    {
        float* encB = out + (long)OFF_ENC + (long)n0 * KCODES;
        #pragma unroll 4
        for (int i = 0; i < 32; i++) {
            int f  = i * 1024 + tid * 4;
            int p  = f >> 9;
            int k0 = f & 511;
            int fd = fidx[p];
            f32x4 v;
            v.x = (k0     == fd) ? 1.0f : 0.0f;
            v.y = (k0 + 1 == fd) ? 1.0f : 0.0f;
            v.z = (k0 + 2 == fd) ? 1.0f : 0.0f;
            v.w = (k0 + 3 == fd) ? 1.0f : 0.0f;
            __builtin_nontemporal_store(v, (f32x4*)(encB + f));
        }
    }
    __syncthreads();   // qs staged before transpose reads

    // ---- quantized_flat [n][64] ----
    {
        float* qfB = out + (long)OFF_QF + (long)n0 * DIMS;
        #pragma unroll
        for (int i = 0; i < 4; i++) {
            int f = i * 1024 + tid * 4;
            int p = f >> 6;
            int d = f & 63;
            f32x4 v;
            v.x = qs[p * 65 + d];     v.y = qs[p * 65 + d + 1];
            v.z = qs[p * 65 + d + 2]; v.w = qs[p * 65 + d + 3];
            __builtin_nontemporal_store(v, (f32x4*)(qfB + f));
        }
    }

    // ---- quantized_out NCHW: 1024 float4 per block (4/thread) ----
    {
        float* qoB = out + (long)OFF_QOUT + (long)b * (DIMS * HW) + hw0;
        #pragma unroll
        for (int i = 0; i < 4; i++) {
            int f4  = i * 256 + tid;
            int d   = f4 >> 4;        // row 0..63
            int seg = f4 & 15;        // float4 segment within row
            f32x4 v;
            v.x = qs[(seg * 4    ) * 65 + d];
            v.y = qs[(seg * 4 + 1) * 65 + d];
            v.z = qs[(seg * 4 + 2) * 65 + d];
            v.w = qs[(seg * 4 + 3) * 65 + d];
            __builtin_nontemporal_store(v, (f32x4*)(qoB + (long)d * HW + seg * 4));
        }
    }
}

// ---------------------------------------------------------------------------
// Finalize: loss scalar + perplexity (fp64)
// ---------------------------------------------------------------------------
__global__ void vq_finalize(const unsigned* __restrict__ hist,
                            const float* __restrict__ bloss,
                            float* __restrict__ out)
{
    __shared__ double sl[512];
    __shared__ double sh[512];
    int tid = threadIdx.x;   // 512

    double l = (double)bloss[tid] + (double)bloss[tid + 512]
             + (double)bloss[tid + 1024] + (double)bloss[tid + 1536];

    unsigned c = hist[tid];
    double p = (double)c * (1.0 / 131072.0);
    double h = p * log(p + 1e-10);

    sl[tid] = l;
    sh[tid] = h;
    __syncthreads();
    for (int s = 256; s > 0; s >>= 1) {
        if (tid < s) { sl[tid] += sl[tid + s]; sh[tid] += sh[tid + s]; }
        __syncthreads();
    }
    if (tid == 0) {
        out[OFF_LOSS] = (float)(0.25 * sl[0] / 8388608.0);
        out[OFF_PERP] = (float)exp(-sh[0]);
    }
}

// ---------------------------------------------------------------------------
extern "C" void kernel_launch(void* const* d_in, const int* in_sizes, int n_in,
                              void* d_out, int out_size, void* d_ws, size_t ws_size,
                              hipStream_t stream)
{
    const float* in  = (const float*)d_in[0];   // inputs  [32,64,64,64] f32
    const float* emb = (const float*)d_in[1];   // codebook [512,64] f32
    float* out = (float*)d_out;
    char*  ws  = (char*)d_ws;

    unsigned*       hist  = (unsigned*)      (ws + WS_HIST);
    float*          bloss = (float*)         (ws + WS_BLOSS);
    float*          nrm   = (float*)         (ws + WS_NRM);
    unsigned short* eh    = (unsigned short*)(ws + WS_EH);
    unsigned short* el    = (unsigned short*)(ws + WS_EL);

    vq_prep<<<KCODES, 64, 0, stream>>>(emb, eh, el, nrm, hist);
    vq_fused<<<2048, 256, 0, stream>>>(in, emb, eh, el, nrm, hist, bloss, out);
    vq_finalize<<<1, 512, 0, stream>>>(hist, bloss, out);
}